// Round 14
// baseline (406.888 us; speedup 1.0000x reference)
//
#include <hip/hip_runtime.h>
#include <hip/hip_cooperative_groups.h>
#include <float.h>
#include <math.h>

namespace cg = cooperative_groups;

#define BATCH 8
#define CHN   128
#define NPTS  2048
#define KNN   9
#define NOUT  256
#define TOTCNT (BATCH*NPTS*KNN)

typedef __attribute__((ext_vector_type(8))) short short8;
typedef __attribute__((ext_vector_type(4))) float f32x4;

__device__ __forceinline__ unsigned short f2bf(float f) {
    unsigned int u = __float_as_uint(f);
    unsigned int r = (u + 0x7FFFu + ((u >> 16) & 1u)) >> 16;
    return (unsigned short)r;
}
__device__ __forceinline__ float bf2f(unsigned short h) {
    return __uint_as_float(((unsigned int)h) << 16);
}

// ---------------- kernel 1: transpose + bf16 split + 0.5*sqnorm (+ W split + stats zero) ----------------
// grid (8 b, 33): y<32 -> x prep tiles (XCD pin); y==32 -> W split for rows b*64.. + zero stats[b].
__global__ __launch_bounds__(256) void prep_kernel(const float* __restrict__ x,
                                                   const float* __restrict__ W,
                                                   unsigned short* __restrict__ xhi,
                                                   unsigned short* __restrict__ xlo,
                                                   unsigned short* __restrict__ whi,
                                                   unsigned short* __restrict__ wlo,
                                                   float* __restrict__ sqh,
                                                   float* __restrict__ stats) {
    __shared__ float xt[128 * 65];
    __shared__ float psq[256];
    const int b = blockIdx.x, tid = threadIdx.x;
    if (blockIdx.y == 32) {   // W -> Bcat=[W1-W2; W2] hi/lo split + zero this batch's stats copy
        stats[b * 512 + tid] = 0.f;
        stats[b * 512 + 256 + tid] = 0.f;
#pragma unroll
        for (int e = 0; e < 32; ++e) {
            int idx = e * 256 + tid;
            int r = b * 64 + (idx >> 7), c = idx & 127;
            float v = (r < 256) ? (W[r * 256 + c] - W[r * 256 + 128 + c])
                                : W[(r - 256) * 256 + 128 + c];
            unsigned short h = f2bf(v);
            float hf = bf2f(h);
            whi[r * 128 + c] = h;
            wlo[r * 128 + c] = f2bf(v - hf);
        }
        return;
    }
    const int n0 = blockIdx.y * 64;
#pragma unroll 4
    for (int p = 0; p < 32; ++p) {
        int c = p * 4 + (tid >> 6), n = tid & 63;
        xt[c * 65 + n] = x[((size_t)b * CHN + c) * NPTS + n0 + n];
    }
    __syncthreads();
    const int n = tid >> 2, cq = tid & 3;
    size_t row = (size_t)(b * NPTS + n0 + n) * CHN;
    float s = 0.f;
#pragma unroll 8
    for (int j = 0; j < 32; ++j) {
        int c = cq * 32 + j;
        float f = xt[c * 65 + n];
        unsigned short h = f2bf(f);
        float hf = bf2f(h);
        unsigned short l = f2bf(f - hf);
        xhi[row + c] = h;
        xlo[row + c] = l;
        s += f * f;
    }
    psq[tid] = s;
    __syncthreads();
    if (tid < 64)
        sqh[b * NPTS + n0 + tid] =
            0.5f * (psq[tid*4] + psq[tid*4+1] + psq[tid*4+2] + psq[tid*4+3]);
}

// ---------------- kernel 2: MFMA split-bf16 distance + top-9 (R7 structure — FROZEN) ----------------
__global__ __launch_bounds__(256) void knn_mfma(const unsigned short* __restrict__ xhi,
                                                const unsigned short* __restrict__ xlo,
                                                const float* __restrict__ sqh,
                                                float* __restrict__ pd,
                                                int* __restrict__ pi) {
    __shared__ __align__(16) float dts[64 * 132];   // 33792 B

    const int tid = threadIdx.x;
    const int b = blockIdx.x, q0 = blockIdx.y * 64, ms = blockIdx.z;
    const int msbase = ms * 512;
    const int wv = tid >> 6, lane = tid & 63;
    const int quad = lane >> 4, col = lane & 15;
    const int koff = quad * 8;
    const int mcol0 = wv * 32;
    const size_t xb = (size_t)b * NPTS * CHN;

    float dl[KNN]; int il[KNN];
#pragma unroll
    for (int k = 0; k < KNN; ++k) { dl[k] = FLT_MAX; il[k] = 0; }

    const int qsc = tid >> 2, ss = tid & 3;
    const int cb = ss * 32;

    auto ins = [&](float v, int idx) {
        if (v < dl[KNN - 1]) {
            bool c0b = v < dl[0];
#pragma unroll
            for (int k = KNN - 1; k >= 1; --k) {
                bool sh   = v < dl[k - 1];
                bool here = v < dl[k];
                float nd = sh ? dl[k - 1] : (here ? v : dl[k]);
                int   ni = sh ? il[k - 1] : (here ? idx : il[k]);
                dl[k] = nd; il[k] = ni;
            }
            if (c0b) { dl[0] = v; il[0] = idx; }
        }
    };

    for (int iter = 0; iter < 4; ++iter) {
        const int mbase = msbase + iter * 128;
        float sm[2];
#pragma unroll
        for (int j = 0; j < 2; ++j)
            sm[j] = sqh[b * NPTS + mbase + mcol0 + j * 16 + col];

        f32x4 acc[4][2];
#pragma unroll
        for (int i = 0; i < 4; ++i)
#pragma unroll
            for (int j = 0; j < 2; ++j) acc[i][j] = (f32x4)0.f;

        for (int chk = 0; chk < 4; ++chk) {
            short8 ah[4], al[4];
#pragma unroll
            for (int i = 0; i < 4; ++i) {
                size_t g = xb + (size_t)(q0 + i * 16 + col) * CHN + chk * 32 + koff;
                ah[i] = *(const short8*)&xhi[g];
                al[i] = *(const short8*)&xlo[g];
            }
#pragma unroll
            for (int j = 0; j < 2; ++j) {
                size_t g = xb + (size_t)(mbase + mcol0 + j * 16 + col) * CHN + chk * 32 + koff;
                short8 bh = *(const short8*)&xhi[g];
                short8 bl = *(const short8*)&xlo[g];
#pragma unroll
                for (int i = 0; i < 4; ++i) {
                    acc[i][j] = __builtin_amdgcn_mfma_f32_16x16x32_bf16(ah[i], bh, acc[i][j], 0, 0, 0);
                    acc[i][j] = __builtin_amdgcn_mfma_f32_16x16x32_bf16(ah[i], bl, acc[i][j], 0, 0, 0);
                    acc[i][j] = __builtin_amdgcn_mfma_f32_16x16x32_bf16(al[i], bh, acc[i][j], 0, 0, 0);
                }
            }
        }

        __syncthreads();
#pragma unroll
        for (int j = 0; j < 2; ++j)
#pragma unroll
            for (int i = 0; i < 4; ++i)
#pragma unroll
                for (int r = 0; r < 4; ++r) {
                    int q_ = i * 16 + quad * 4 + r;
                    dts[q_ * 132 + mcol0 + j * 16 + col] = sm[j] - acc[i][j][r];
                }
        __syncthreads();
        const int ibase = mbase + cb;
#pragma unroll
        for (int jj = 0; jj < 8; ++jj) {
            float4 v = *(const float4*)&dts[qsc * 132 + cb + jj * 4];
            float mn4 = fminf(fminf(v.x, v.y), fminf(v.z, v.w));
            if (mn4 < dl[KNN - 1]) {
                int ib = ibase + jj * 4;
                ins(v.x, ib); ins(v.y, ib + 1); ins(v.z, ib + 2); ins(v.w, ib + 3);
            }
        }
    }

    __syncthreads();
    float* md = dts;
    int*   mi = (int*)(dts + 2304);
#pragma unroll
    for (int k = 0; k < KNN; ++k) {
        md[qsc * 36 + ss * 9 + k] = dl[k];
        mi[qsc * 36 + ss * 9 + k] = il[k];
    }
    __syncthreads();
    if (tid < 64) {
        int base = tid * 36;
        int p0 = 0, p1 = 0, p2 = 0, p3 = 0;
        size_t ob = ((size_t)(b * NPTS + q0 + tid) * 4 + ms) * KNN;
        for (int k = 0; k < KNN; ++k) {
            float v0 = (p0 < KNN) ? md[base + p0]      : FLT_MAX;
            float v1 = (p1 < KNN) ? md[base + 9 + p1]  : FLT_MAX;
            float v2 = (p2 < KNN) ? md[base + 18 + p2] : FLT_MAX;
            float v3 = (p3 < KNN) ? md[base + 27 + p3] : FLT_MAX;
            float best = v0; int sel = 0;
            if (v1 < best) { best = v1; sel = 1; }
            if (v2 < best) { best = v2; sel = 2; }
            if (v3 < best) { best = v3; sel = 3; }
            int idx;
            if      (sel == 0) { idx = mi[base + p0];      p0++; }
            else if (sel == 1) { idx = mi[base + 9 + p1];  p1++; }
            else if (sel == 2) { idx = mi[base + 18 + p2]; p2++; }
            else               { idx = mi[base + 27 + p3]; p3++; }
            pd[ob + k] = best;
            pi[ob + k] = idx;
        }
    }
}

// ---------------- kernel 3: p = x*(W1-W2)^T (fp32), q = x*W2^T (bf16) via MFMA (FROZEN) ----------------
__global__ __launch_bounds__(256) void pq_mfma(const unsigned short* __restrict__ xhi,
                                               const unsigned short* __restrict__ xlo,
                                               const unsigned short* __restrict__ whi,
                                               const unsigned short* __restrict__ wlo,
                                               float* __restrict__ p,
                                               unsigned short* __restrict__ q) {
    const int tid = threadIdx.x;
    const int b = blockIdx.x, nt = blockIdx.y, ot = blockIdx.z;
    const int wv = tid >> 6, lane = tid & 63;
    const int quad = lane >> 4, col = lane & 15;
    const int koff = quad * 8;
    const size_t xb = (size_t)b * NPTS * CHN;
    const int nbase = nt * 256 + wv * 64;
    const int obase = ot * 64;

    f32x4 acc[4][4];
#pragma unroll
    for (int i = 0; i < 4; ++i)
#pragma unroll
        for (int j = 0; j < 4; ++j) acc[i][j] = (f32x4)0.f;

    for (int chk = 0; chk < 4; ++chk) {
        short8 ah[4], al[4];
#pragma unroll
        for (int i = 0; i < 4; ++i) {
            size_t g = xb + (size_t)(nbase + i * 16 + col) * CHN + chk * 32 + koff;
            ah[i] = *(const short8*)&xhi[g];
            al[i] = *(const short8*)&xlo[g];
        }
#pragma unroll
        for (int j = 0; j < 4; ++j) {
            size_t g = (size_t)(obase + j * 16 + col) * CHN + chk * 32 + koff;
            short8 bh = *(const short8*)&whi[g];
            short8 bl = *(const short8*)&wlo[g];
#pragma unroll
            for (int i = 0; i < 4; ++i) {
                acc[i][j] = __builtin_amdgcn_mfma_f32_16x16x32_bf16(ah[i], bh, acc[i][j], 0, 0, 0);
                acc[i][j] = __builtin_amdgcn_mfma_f32_16x16x32_bf16(ah[i], bl, acc[i][j], 0, 0, 0);
                acc[i][j] = __builtin_amdgcn_mfma_f32_16x16x32_bf16(al[i], bh, acc[i][j], 0, 0, 0);
            }
        }
    }
#pragma unroll
    for (int i = 0; i < 4; ++i)
#pragma unroll
        for (int j = 0; j < 4; ++j) {
            int oc = (obase + j * 16 + col) & 255;
#pragma unroll
            for (int r = 0; r < 4; ++r) {
                int n = nbase + i * 16 + quad * 4 + r;
                size_t off = (size_t)(b * NPTS + n) * NOUT + oc;
                if (ot < 4) p[off] = acc[i][j][r];
                else        q[off] = f2bf(acc[i][j][r]);
            }
        }
}

// ---------------- kernel 4: COOPERATIVE merge + gather + BN stats | grid-sync | normalize + store ----------
// grid (8 b, 128 ntile-of-16) = 1024 blocks; blockIdx.x = b -> XCD pin.
// R13's proven stats2 shape (16 q/block, 2-q unroll, per-batch atomics); packed (hmax,hmin)
// bf16 pair held in LDS across grid.sync -> hmm global round-trip (32 MB) + one dispatch deleted.
// (R10's coop failure was 32q/no-unroll/global-chain/VGPR52 — all four causes fixed here.)
__global__ __launch_bounds__(256) void fused_tail_kernel(const float* __restrict__ p,
                                                         const unsigned short* __restrict__ q,
                                                         const float* __restrict__ pd,
                                                         const int* __restrict__ pi,
                                                         float* __restrict__ stats,
                                                         const float* __restrict__ gamma,
                                                         const float* __restrict__ beta,
                                                         float* __restrict__ out) {
    __shared__ unsigned int hmm_s[16 * 257];            // 16448 B packed (hmax<<16)|hmin
    __shared__ int   idx_s[16 * KNN];                   //   576 B
    __shared__ float g_s[256], bet_s[256], mean_s[256]; //  3072 B
    const int b = blockIdx.x, n0 = blockIdx.y * 16;
    const int o = threadIdx.x;

    if (threadIdx.x < 16) {     // merge the 4 sorted per-quarter top-9 lists
        size_t g = (size_t)(b * NPTS + n0 + threadIdx.x) * 36;
        const float* d = pd + g;
        const int*   i = pi + g;
        int p0 = 0, p1 = 0, p2 = 0, p3 = 0;
#pragma unroll
        for (int k = 0; k < KNN; ++k) {
            float v0 = (p0 < KNN) ? d[p0]      : FLT_MAX;
            float v1 = (p1 < KNN) ? d[9 + p1]  : FLT_MAX;
            float v2 = (p2 < KNN) ? d[18 + p2] : FLT_MAX;
            float v3 = (p3 < KNN) ? d[27 + p3] : FLT_MAX;
            float best = v0; int sel = 0;
            if (v1 < best) { best = v1; sel = 1; }
            if (v2 < best) { best = v2; sel = 2; }
            if (v3 < best) { best = v3; sel = 3; }
            int idx;
            if      (sel == 0) { idx = i[p0];      p0++; }
            else if (sel == 1) { idx = i[9 + p1];  p1++; }
            else if (sel == 2) { idx = i[18 + p2]; p2++; }
            else               { idx = i[27 + p3]; p3++; }
            idx_s[threadIdx.x * KNN + k] = idx;
        }
    }
    __syncthreads();

    const unsigned short* qb = q + (size_t)b * NPTS * NOUT + o;
    float s = 0.f, ss = 0.f;
    for (int qq = 0; qq < 16; qq += 2) {
        size_t off0 = (size_t)(b * NPTS + n0 + qq) * NOUT + o;
        size_t off1 = off0 + NOUT;
        float pv0 = p[off0], pv1 = p[off1];
        float h0[KNN], h1[KNN];
#pragma unroll
        for (int k = 0; k < KNN; ++k)
            h0[k] = bf2f(qb[(size_t)idx_s[qq * KNN + k] * NOUT]);
#pragma unroll
        for (int k = 0; k < KNN; ++k)
            h1[k] = bf2f(qb[(size_t)idx_s[(qq + 1) * KNN + k] * NOUT]);
        float mx0 = -FLT_MAX, mn0 = FLT_MAX, mx1 = -FLT_MAX, mn1 = FLT_MAX;
#pragma unroll
        for (int k = 0; k < KNN; ++k) {
            float a = pv0 + h0[k], c = pv1 + h1[k];
            s += a + c; ss += a * a + c * c;
            mx0 = fmaxf(mx0, a); mn0 = fminf(mn0, a);
            mx1 = fmaxf(mx1, c); mn1 = fminf(mn1, c);
        }
        hmm_s[qq * 257 + o]       = ((unsigned int)f2bf(mx0) << 16) | f2bf(mn0);
        hmm_s[(qq + 1) * 257 + o] = ((unsigned int)f2bf(mx1) << 16) | f2bf(mn1);
    }
    atomicAdd(&stats[b * 512 + o], s);
    atomicAdd(&stats[b * 512 + NOUT + o], ss);
    __threadfence();
    cg::this_grid().sync();

    {   // per-channel BN constants (sum the 8 per-batch copies)
        float sum = 0.f, sumsq = 0.f;
#pragma unroll
        for (int i = 0; i < 8; ++i) {
            sum   += stats[i * 512 + o];
            sumsq += stats[i * 512 + NOUT + o];
        }
        const float inv = 1.f / (float)TOTCNT;
        float mean = sum * inv;
        float var  = sumsq * inv - mean * mean;
        g_s[o]    = gamma[o] / sqrtf(var + 1e-5f);
        bet_s[o]  = beta[o];
        mean_s[o] = mean;
    }
    __syncthreads();

    const int oo = threadIdx.x >> 4, qq2 = threadIdx.x & 15;
    for (int pass = 0; pass < 16; ++pass) {
        int o_ = pass * 16 + oo;
        float g = g_s[o_];
        unsigned int w = hmm_s[qq2 * 257 + o_];
        float v = bf2f((g >= 0.f) ? (unsigned short)(w >> 16) : (unsigned short)(w & 0xFFFFu));
        float hn = (v - mean_s[o_]) * g + bet_s[o_];
        out[((size_t)b * NOUT + o_) * NPTS + n0 + qq2] = fmaxf(hn, 0.f);
    }
}

extern "C" void kernel_launch(void* const* d_in, const int* in_sizes, int n_in,
                              void* d_out, int out_size, void* d_ws, size_t ws_size,
                              hipStream_t stream) {
    (void)in_sizes; (void)n_in; (void)out_size; (void)ws_size;
    const float* x     = (const float*)d_in[0];
    const float* W     = (const float*)d_in[1];
    const float* gamma = (const float*)d_in[2];
    const float* beta  = (const float*)d_in[3];
    float* out = (float*)d_out;

    char* ws = (char*)d_ws;
    float*          p     = (float*)ws;                                   // 16 MB fp32
    unsigned short* q     = (unsigned short*)(ws + (16u << 20));          // 8 MB bf16
    unsigned short* xhi   = (unsigned short*)(ws + (24u << 20));          // 4 MB
    unsigned short* xlo   = (unsigned short*)(ws + (28u << 20));          // 4 MB
    unsigned short* whi   = (unsigned short*)(ws + (32u << 20));          // 128 KB
    unsigned short* wlo   = (unsigned short*)(ws + (32u << 20) + 131072); // 128 KB
    float*          pd    = (float*)(ws + (33u << 20));                   // 2.25 MB
    int*            pi    = (int*)  (ws + (36u << 20));                   // 2.25 MB
    float*          sqh   = (float*)(ws + (39u << 20));                   // 64 KB
    float*          stats = (float*)(ws + (39u << 20) + 65536);           // 16 KB

    prep_kernel<<<dim3(8, 33),    256, 0, stream>>>(x, W, xhi, xlo, whi, wlo, sqh, stats);
    knn_mfma   <<<dim3(8, 32, 4), 256, 0, stream>>>(xhi, xlo, sqh, pd, pi);
    pq_mfma    <<<dim3(8, 8, 8),  256, 0, stream>>>(xhi, xlo, whi, wlo, p, q);

    void* fargs[] = { (void*)&p, (void*)&q, (void*)&pd, (void*)&pi,
                      (void*)&stats, (void*)&gamma, (void*)&beta, (void*)&out };
    hipLaunchCooperativeKernel((void*)fused_tail_kernel, dim3(8, 128), dim3(256),
                               fargs, 0, stream);
}

// Round 15
// 209.531 us; speedup vs baseline: 1.9419x; 1.9419x over previous
//
#include <hip/hip_runtime.h>
#include <float.h>
#include <math.h>

#define BATCH 8
#define CHN   128
#define NPTS  2048
#define KNN   9
#define NOUT  256
#define TOTCNT (BATCH*NPTS*KNN)

typedef __attribute__((ext_vector_type(8))) short short8;
typedef __attribute__((ext_vector_type(4))) float f32x4;

__device__ __forceinline__ unsigned short f2bf(float f) {
    unsigned int u = __float_as_uint(f);
    unsigned int r = (u + 0x7FFFu + ((u >> 16) & 1u)) >> 16;
    return (unsigned short)r;
}
__device__ __forceinline__ float bf2f(unsigned short h) {
    return __uint_as_float(((unsigned int)h) << 16);
}

// ---------------- kernel 1: transpose + bf16 split + 0.5*sqnorm (+ W split + stats zero) ----------------
// grid (8 b, 33): y<32 -> x prep tiles (XCD pin); y==32 -> W split rows b*64.. + zero stats[b].
__global__ __launch_bounds__(256) void prep_kernel(const float* __restrict__ x,
                                                   const float* __restrict__ W,
                                                   unsigned short* __restrict__ xhi,
                                                   unsigned short* __restrict__ xlo,
                                                   unsigned short* __restrict__ whi,
                                                   unsigned short* __restrict__ wlo,
                                                   float* __restrict__ sqh,
                                                   float* __restrict__ stats) {
    __shared__ float xt[128 * 65];
    __shared__ float psq[256];
    const int b = blockIdx.x, tid = threadIdx.x;
    if (blockIdx.y == 32) {   // W -> Bcat=[W1-W2; W2] hi/lo split + zero this batch's stats copy
        stats[b * 512 + tid] = 0.f;
        stats[b * 512 + 256 + tid] = 0.f;
#pragma unroll
        for (int e = 0; e < 32; ++e) {
            int idx = e * 256 + tid;
            int r = b * 64 + (idx >> 7), c = idx & 127;
            float v = (r < 256) ? (W[r * 256 + c] - W[r * 256 + 128 + c])
                                : W[(r - 256) * 256 + 128 + c];
            unsigned short h = f2bf(v);
            float hf = bf2f(h);
            whi[r * 128 + c] = h;
            wlo[r * 128 + c] = f2bf(v - hf);
        }
        return;
    }
    const int n0 = blockIdx.y * 64;
#pragma unroll 4
    for (int p = 0; p < 32; ++p) {
        int c = p * 4 + (tid >> 6), n = tid & 63;
        xt[c * 65 + n] = x[((size_t)b * CHN + c) * NPTS + n0 + n];
    }
    __syncthreads();
    const int n = tid >> 2, cq = tid & 3;
    size_t row = (size_t)(b * NPTS + n0 + n) * CHN;
    float s = 0.f;
#pragma unroll 8
    for (int j = 0; j < 32; ++j) {
        int c = cq * 32 + j;
        float f = xt[c * 65 + n];
        unsigned short h = f2bf(f);
        float hf = bf2f(h);
        unsigned short l = f2bf(f - hf);
        xhi[row + c] = h;
        xlo[row + c] = l;
        s += f * f;
    }
    psq[tid] = s;
    __syncthreads();
    if (tid < 64)
        sqh[b * NPTS + n0 + tid] =
            0.5f * (psq[tid*4] + psq[tid*4+1] + psq[tid*4+2] + psq[tid*4+3]);
}

// ---------------- kernel 2: knn (R7 structure, FROZEN) + register-BALANCED pq in one dispatch -------------
// grid (8 b, 32, 8): z<4 -> knn m-quarter z; z>=4 -> pq block nt=y>>2, ot=((y&3)<<2)|(z-4).
// pq path uses acc[4][2] (64n x 32o per wave, ~90 regs peak) so the SHARED allocation stays at
// knn's natural ~120 (R11's failure: pq acc[4][4] pushed it to 148 -> knn lost latency hiding).
// pq's MFMA-dense blocks backfill knn's ~50% idle cycles -> pq's ~25us serial time disappears.
__global__ __launch_bounds__(256) void knnpq_mfma(const unsigned short* __restrict__ xhi,
                                                  const unsigned short* __restrict__ xlo,
                                                  const float* __restrict__ sqh,
                                                  const unsigned short* __restrict__ whi,
                                                  const unsigned short* __restrict__ wlo,
                                                  float* __restrict__ pd,
                                                  int* __restrict__ pi,
                                                  float* __restrict__ p,
                                                  unsigned short* __restrict__ q) {
    __shared__ __align__(16) float dts[64 * 132];   // 33792 B (knn path only)

    const int tid = threadIdx.x;
    const int b = blockIdx.x;
    const int wv = tid >> 6, lane = tid & 63;
    const int quad = lane >> 4, col = lane & 15;
    const int koff = quad * 8;
    const size_t xb = (size_t)b * NPTS * CHN;

    if (blockIdx.z >= 4) {
        // ---------------- pq path: 256n x 32o per block, acc[4][2] per wave ----------------
        const int nt = blockIdx.y >> 2;
        const int ot = ((blockIdx.y & 3) << 2) | (blockIdx.z - 4);   // 0..15
        const int nbase = nt * 256 + wv * 64;
        const int obase = ot * 32;                                    // row in Bcat [512]

        f32x4 acc[4][2];
#pragma unroll
        for (int i = 0; i < 4; ++i)
#pragma unroll
            for (int j = 0; j < 2; ++j) acc[i][j] = (f32x4)0.f;

        for (int chk = 0; chk < 4; ++chk) {
            short8 ah[4], al[4];
#pragma unroll
            for (int i = 0; i < 4; ++i) {
                size_t g = xb + (size_t)(nbase + i * 16 + col) * CHN + chk * 32 + koff;
                ah[i] = *(const short8*)&xhi[g];
                al[i] = *(const short8*)&xlo[g];
            }
#pragma unroll
            for (int j = 0; j < 2; ++j) {
                size_t g = (size_t)(obase + j * 16 + col) * CHN + chk * 32 + koff;
                short8 bh = *(const short8*)&whi[g];
                short8 bl = *(const short8*)&wlo[g];
#pragma unroll
                for (int i = 0; i < 4; ++i) {
                    acc[i][j] = __builtin_amdgcn_mfma_f32_16x16x32_bf16(ah[i], bh, acc[i][j], 0, 0, 0);
                    acc[i][j] = __builtin_amdgcn_mfma_f32_16x16x32_bf16(ah[i], bl, acc[i][j], 0, 0, 0);
                    acc[i][j] = __builtin_amdgcn_mfma_f32_16x16x32_bf16(al[i], bh, acc[i][j], 0, 0, 0);
                }
            }
        }
#pragma unroll
        for (int i = 0; i < 4; ++i)
#pragma unroll
            for (int j = 0; j < 2; ++j) {
                int brow = obase + j * 16 + col;
                int oc = brow & 255;
#pragma unroll
                for (int r = 0; r < 4; ++r) {
                    int n = nbase + i * 16 + quad * 4 + r;
                    size_t off = (size_t)(b * NPTS + n) * NOUT + oc;
                    if (ot < 8) p[off] = acc[i][j][r];
                    else        q[off] = f2bf(acc[i][j][r]);
                }
            }
        return;
    }

    // ---------------- knn path (R7 structure — FROZEN) ----------------
    const int q0 = blockIdx.y * 64, ms = blockIdx.z;
    const int msbase = ms * 512;
    const int mcol0 = wv * 32;

    float dl[KNN]; int il[KNN];
#pragma unroll
    for (int k = 0; k < KNN; ++k) { dl[k] = FLT_MAX; il[k] = 0; }

    const int qsc = tid >> 2, ss = tid & 3;
    const int cb = ss * 32;

    auto ins = [&](float v, int idx) {
        if (v < dl[KNN - 1]) {
            bool c0b = v < dl[0];
#pragma unroll
            for (int k = KNN - 1; k >= 1; --k) {
                bool sh   = v < dl[k - 1];
                bool here = v < dl[k];
                float nd = sh ? dl[k - 1] : (here ? v : dl[k]);
                int   ni = sh ? il[k - 1] : (here ? idx : il[k]);
                dl[k] = nd; il[k] = ni;
            }
            if (c0b) { dl[0] = v; il[0] = idx; }
        }
    };

    for (int iter = 0; iter < 4; ++iter) {
        const int mbase = msbase + iter * 128;
        float sm[2];
#pragma unroll
        for (int j = 0; j < 2; ++j)
            sm[j] = sqh[b * NPTS + mbase + mcol0 + j * 16 + col];

        f32x4 acc[4][2];
#pragma unroll
        for (int i = 0; i < 4; ++i)
#pragma unroll
            for (int j = 0; j < 2; ++j) acc[i][j] = (f32x4)0.f;

        for (int chk = 0; chk < 4; ++chk) {
            short8 ah[4], al[4];
#pragma unroll
            for (int i = 0; i < 4; ++i) {
                size_t g = xb + (size_t)(q0 + i * 16 + col) * CHN + chk * 32 + koff;
                ah[i] = *(const short8*)&xhi[g];
                al[i] = *(const short8*)&xlo[g];
            }
#pragma unroll
            for (int j = 0; j < 2; ++j) {
                size_t g = xb + (size_t)(mbase + mcol0 + j * 16 + col) * CHN + chk * 32 + koff;
                short8 bh = *(const short8*)&xhi[g];
                short8 bl = *(const short8*)&xlo[g];
#pragma unroll
                for (int i = 0; i < 4; ++i) {
                    acc[i][j] = __builtin_amdgcn_mfma_f32_16x16x32_bf16(ah[i], bh, acc[i][j], 0, 0, 0);
                    acc[i][j] = __builtin_amdgcn_mfma_f32_16x16x32_bf16(ah[i], bl, acc[i][j], 0, 0, 0);
                    acc[i][j] = __builtin_amdgcn_mfma_f32_16x16x32_bf16(al[i], bh, acc[i][j], 0, 0, 0);
                }
            }
        }

        __syncthreads();
#pragma unroll
        for (int j = 0; j < 2; ++j)
#pragma unroll
            for (int i = 0; i < 4; ++i)
#pragma unroll
                for (int r = 0; r < 4; ++r) {
                    int q_ = i * 16 + quad * 4 + r;
                    dts[q_ * 132 + mcol0 + j * 16 + col] = sm[j] - acc[i][j][r];
                }
        __syncthreads();
        const int ibase = mbase + cb;
#pragma unroll
        for (int jj = 0; jj < 8; ++jj) {
            float4 v = *(const float4*)&dts[qsc * 132 + cb + jj * 4];
            float mn4 = fminf(fminf(v.x, v.y), fminf(v.z, v.w));
            if (mn4 < dl[KNN - 1]) {
                int ib = ibase + jj * 4;
                ins(v.x, ib); ins(v.y, ib + 1); ins(v.z, ib + 2); ins(v.w, ib + 3);
            }
        }
    }

    __syncthreads();
    float* md = dts;
    int*   mi = (int*)(dts + 2304);
#pragma unroll
    for (int k = 0; k < KNN; ++k) {
        md[qsc * 36 + ss * 9 + k] = dl[k];
        mi[qsc * 36 + ss * 9 + k] = il[k];
    }
    __syncthreads();
    if (tid < 64) {
        int base = tid * 36;
        int p0 = 0, p1 = 0, p2 = 0, p3 = 0;
        size_t ob = ((size_t)(b * NPTS + q0 + tid) * 4 + ms) * KNN;
        for (int k = 0; k < KNN; ++k) {
            float v0 = (p0 < KNN) ? md[base + p0]      : FLT_MAX;
            float v1 = (p1 < KNN) ? md[base + 9 + p1]  : FLT_MAX;
            float v2 = (p2 < KNN) ? md[base + 18 + p2] : FLT_MAX;
            float v3 = (p3 < KNN) ? md[base + 27 + p3] : FLT_MAX;
            float best = v0; int sel = 0;
            if (v1 < best) { best = v1; sel = 1; }
            if (v2 < best) { best = v2; sel = 2; }
            if (v3 < best) { best = v3; sel = 3; }
            int idx;
            if      (sel == 0) { idx = mi[base + p0];      p0++; }
            else if (sel == 1) { idx = mi[base + 9 + p1];  p1++; }
            else if (sel == 2) { idx = mi[base + 18 + p2]; p2++; }
            else               { idx = mi[base + 27 + p3]; p3++; }
            pd[ob + k] = best;
            pi[ob + k] = idx;
        }
    }
}

// ---------------- kernel 3: merge FUSED + BN stats (per-batch) + packed bf16 (hmax,hmin) (R13) ------------
// grid (8 b, 128 ntile-of-16) = 1024 blocks; blockIdx.x = b -> XCD pin.
__global__ __launch_bounds__(256) void stats2_kernel(const float* __restrict__ p,
                                                     const unsigned short* __restrict__ q,
                                                     const float* __restrict__ pd,
                                                     const int* __restrict__ pi,
                                                     float* __restrict__ stats,
                                                     unsigned int* __restrict__ hmm) {
    __shared__ int idx_s[16 * KNN];
    const int b = blockIdx.x, n0 = blockIdx.y * 16;
    const int o = threadIdx.x;
    if (threadIdx.x < 16) {
        size_t g = (size_t)(b * NPTS + n0 + threadIdx.x) * 36;
        const float* d = pd + g;
        const int*   i = pi + g;
        int p0 = 0, p1 = 0, p2 = 0, p3 = 0;
#pragma unroll
        for (int k = 0; k < KNN; ++k) {
            float v0 = (p0 < KNN) ? d[p0]      : FLT_MAX;
            float v1 = (p1 < KNN) ? d[9 + p1]  : FLT_MAX;
            float v2 = (p2 < KNN) ? d[18 + p2] : FLT_MAX;
            float v3 = (p3 < KNN) ? d[27 + p3] : FLT_MAX;
            float best = v0; int sel = 0;
            if (v1 < best) { best = v1; sel = 1; }
            if (v2 < best) { best = v2; sel = 2; }
            if (v3 < best) { best = v3; sel = 3; }
            int idx;
            if      (sel == 0) { idx = i[p0];      p0++; }
            else if (sel == 1) { idx = i[9 + p1];  p1++; }
            else if (sel == 2) { idx = i[18 + p2]; p2++; }
            else               { idx = i[27 + p3]; p3++; }
            idx_s[threadIdx.x * KNN + k] = idx;
        }
    }
    __syncthreads();
    const unsigned short* qb = q + (size_t)b * NPTS * NOUT + o;
    float s = 0.f, ss = 0.f;
    for (int qq = 0; qq < 16; qq += 2) {
        size_t off0 = (size_t)(b * NPTS + n0 + qq) * NOUT + o;
        size_t off1 = off0 + NOUT;
        float pv0 = p[off0], pv1 = p[off1];
        float h0[KNN], h1[KNN];
#pragma unroll
        for (int k = 0; k < KNN; ++k)
            h0[k] = bf2f(qb[(size_t)idx_s[qq * KNN + k] * NOUT]);
#pragma unroll
        for (int k = 0; k < KNN; ++k)
            h1[k] = bf2f(qb[(size_t)idx_s[(qq + 1) * KNN + k] * NOUT]);
        float mx0 = -FLT_MAX, mn0 = FLT_MAX, mx1 = -FLT_MAX, mn1 = FLT_MAX;
#pragma unroll
        for (int k = 0; k < KNN; ++k) {
            float a = pv0 + h0[k], c = pv1 + h1[k];
            s += a + c; ss += a * a + c * c;
            mx0 = fmaxf(mx0, a); mn0 = fminf(mn0, a);
            mx1 = fmaxf(mx1, c); mn1 = fminf(mn1, c);
        }
        hmm[off0] = ((unsigned int)f2bf(mx0) << 16) | f2bf(mn0);
        hmm[off1] = ((unsigned int)f2bf(mx1) << 16) | f2bf(mn1);
    }
    atomicAdd(&stats[b * 512 + o], s);
    atomicAdd(&stats[b * 512 + NOUT + o], ss);
}

// ---------------- kernel 4: normalize + relu + max_k, transposed store (R13) ----------------
__global__ __launch_bounds__(256) void final_kernel(const unsigned int* __restrict__ hmm,
                                                    const float* __restrict__ stats,
                                                    const float* __restrict__ gamma,
                                                    const float* __restrict__ beta,
                                                    float* __restrict__ out) {
    __shared__ float tr[256 * 17];
    const int b = blockIdx.x, n0 = blockIdx.y * 16;
    const int o = threadIdx.x;
    float sum = 0.f, sumsq = 0.f;
#pragma unroll
    for (int i = 0; i < 8; ++i) {
        sum   += stats[i * 512 + o];
        sumsq += stats[i * 512 + NOUT + o];
    }
    const float inv = 1.f / (float)TOTCNT;
    float mean = sum * inv;
    float var  = sumsq * inv - mean * mean;
    float g    = gamma[o] / sqrtf(var + 1e-5f);
    float bet  = beta[o];
    const bool pos = (g >= 0.f);
    for (int qq = 0; qq < 16; ++qq) {
        size_t off = (size_t)(b * NPTS + n0 + qq) * NOUT + o;
        unsigned int w = hmm[off];
        float v = bf2f(pos ? (unsigned short)(w >> 16) : (unsigned short)(w & 0xFFFFu));
        float hn = (v - mean) * g + bet;
        tr[o * 17 + qq] = fmaxf(hn, 0.f);
    }
    __syncthreads();
    int oo = threadIdx.x >> 4, qq = threadIdx.x & 15;
    for (int pass = 0; pass < 16; ++pass) {
        int o_ = pass * 16 + oo;
        out[((size_t)b * NOUT + o_) * NPTS + n0 + qq] = tr[o_ * 17 + qq];
    }
}

extern "C" void kernel_launch(void* const* d_in, const int* in_sizes, int n_in,
                              void* d_out, int out_size, void* d_ws, size_t ws_size,
                              hipStream_t stream) {
    (void)in_sizes; (void)n_in; (void)out_size; (void)ws_size;
    const float* x     = (const float*)d_in[0];
    const float* W     = (const float*)d_in[1];
    const float* gamma = (const float*)d_in[2];
    const float* beta  = (const float*)d_in[3];
    float* out = (float*)d_out;

    char* ws = (char*)d_ws;
    float*          p     = (float*)ws;                                   // 16 MB fp32
    unsigned short* q     = (unsigned short*)(ws + (16u << 20));          // 8 MB bf16
    unsigned short* xhi   = (unsigned short*)(ws + (24u << 20));          // 4 MB
    unsigned short* xlo   = (unsigned short*)(ws + (28u << 20));          // 4 MB
    unsigned int*   hmm   = (unsigned int*)(ws + (32u << 20));            // 16 MB
    unsigned short* whi   = (unsigned short*)(ws + (48u << 20));          // 128 KB
    unsigned short* wlo   = (unsigned short*)(ws + (48u << 20) + 131072); // 128 KB
    float*          pd    = (float*)(ws + (49u << 20));                   // 2.25 MB
    int*            pi    = (int*)  (ws + (52u << 20));                   // 2.25 MB
    float*          sqh   = (float*)(ws + (55u << 20));                   // 64 KB
    float*          stats = (float*)(ws + (55u << 20) + 65536);           // 16 KB

    prep_kernel  <<<dim3(8, 33),    256, 0, stream>>>(x, W, xhi, xlo, whi, wlo, sqh, stats);
    knnpq_mfma   <<<dim3(8, 32, 8), 256, 0, stream>>>(xhi, xlo, sqh, whi, wlo, pd, pi, p, q);
    stats2_kernel<<<dim3(8, 128),   256, 0, stream>>>(p, q, pd, pi, stats, hmm);
    final_kernel <<<dim3(8, 128),   256, 0, stream>>>(hmm, stats, gamma, beta, out);
}

// Round 16
// 206.978 us; speedup vs baseline: 1.9659x; 1.0123x over previous
//
#include <hip/hip_runtime.h>
#include <float.h>
#include <math.h>

#define BATCH 8
#define CHN   128
#define NPTS  2048
#define KNN   9
#define NOUT  256
#define TOTCNT (BATCH*NPTS*KNN)

typedef __attribute__((ext_vector_type(8))) short short8;
typedef __attribute__((ext_vector_type(4))) float f32x4;

__device__ __forceinline__ unsigned short f2bf(float f) {
    unsigned int u = __float_as_uint(f);
    unsigned int r = (u + 0x7FFFu + ((u >> 16) & 1u)) >> 16;
    return (unsigned short)r;
}
__device__ __forceinline__ float bf2f(unsigned short h) {
    return __uint_as_float(((unsigned int)h) << 16);
}

// ---------------- kernel 1: transpose + bf16 split + 0.5*sqnorm (+ W split + stats zero) ----------------
__global__ __launch_bounds__(256) void prep_kernel(const float* __restrict__ x,
                                                   const float* __restrict__ W,
                                                   unsigned short* __restrict__ xhi,
                                                   unsigned short* __restrict__ xlo,
                                                   unsigned short* __restrict__ whi,
                                                   unsigned short* __restrict__ wlo,
                                                   float* __restrict__ sqh,
                                                   float* __restrict__ stats) {
    __shared__ float xt[128 * 65];
    __shared__ float psq[256];
    const int b = blockIdx.x, tid = threadIdx.x;
    if (blockIdx.y == 32) {   // W -> Bcat=[W1-W2; W2] hi/lo split + zero this batch's stats copy
        stats[b * 512 + tid] = 0.f;
        stats[b * 512 + 256 + tid] = 0.f;
#pragma unroll
        for (int e = 0; e < 32; ++e) {
            int idx = e * 256 + tid;
            int r = b * 64 + (idx >> 7), c = idx & 127;
            float v = (r < 256) ? (W[r * 256 + c] - W[r * 256 + 128 + c])
                                : W[(r - 256) * 256 + 128 + c];
            unsigned short h = f2bf(v);
            float hf = bf2f(h);
            whi[r * 128 + c] = h;
            wlo[r * 128 + c] = f2bf(v - hf);
        }
        return;
    }
    const int n0 = blockIdx.y * 64;
#pragma unroll 4
    for (int p = 0; p < 32; ++p) {
        int c = p * 4 + (tid >> 6), n = tid & 63;
        xt[c * 65 + n] = x[((size_t)b * CHN + c) * NPTS + n0 + n];
    }
    __syncthreads();
    const int n = tid >> 2, cq = tid & 3;
    size_t row = (size_t)(b * NPTS + n0 + n) * CHN;
    float s = 0.f;
#pragma unroll 8
    for (int j = 0; j < 32; ++j) {
        int c = cq * 32 + j;
        float f = xt[c * 65 + n];
        unsigned short h = f2bf(f);
        float hf = bf2f(h);
        unsigned short l = f2bf(f - hf);
        xhi[row + c] = h;
        xlo[row + c] = l;
        s += f * f;
    }
    psq[tid] = s;
    __syncthreads();
    if (tid < 64)
        sqh[b * NPTS + n0 + tid] =
            0.5f * (psq[tid*4] + psq[tid*4+1] + psq[tid*4+2] + psq[tid*4+3]);
}

// ---------------- kernel 2: knn (R7 MFMA blocking + WAVE-PRIVATE scan, 2 barriers) + balanced pq ---------
// grid (8 b, 32, 8): z<4 -> knn m-quarter z; z>=4 -> pq (nt=y>>2, ot=((y&3)<<2)|(z-4)).
// knn: wave = 64q x 32m slice per iter (acc[4][2], R7's proven 4-A-frag x 2-B-frag loads)
// BUT dump goes to a wave-PRIVATE 64x36 LDS region and lane l scans its OWN query row l
// (top-9 over this wave's 128 m-cols). Same-wave RAW = lgkmcnt only -> 2 barriers/block
// instead of 10 (R7's convoy). R8 proved barrier-free works; R8's regression was the
// lost A-reuse + VGPR 80, both fixed here (~110 regs, loads identical to R7).
__global__ __launch_bounds__(256) void knnpq_mfma(const unsigned short* __restrict__ xhi,
                                                  const unsigned short* __restrict__ xlo,
                                                  const float* __restrict__ sqh,
                                                  const unsigned short* __restrict__ whi,
                                                  const unsigned short* __restrict__ wlo,
                                                  float* __restrict__ pd,
                                                  int* __restrict__ pi,
                                                  float* __restrict__ p,
                                                  unsigned short* __restrict__ q) {
    __shared__ __align__(16) float dts[4 * 64 * 36];   // 36864 B; 9216 B wave-private regions

    const int tid = threadIdx.x;
    const int b = blockIdx.x;
    const int wv = tid >> 6, lane = tid & 63;
    const int quad = lane >> 4, col = lane & 15;
    const int koff = quad * 8;
    const size_t xb = (size_t)b * NPTS * CHN;

    if (blockIdx.z >= 4) {
        // ---------------- pq path: 256n x 32o per block, acc[4][2] per wave (R15-proven) ----------------
        const int nt = blockIdx.y >> 2;
        const int ot = ((blockIdx.y & 3) << 2) | (blockIdx.z - 4);   // 0..15
        const int nbase = nt * 256 + wv * 64;
        const int obase = ot * 32;                                    // row in Bcat [512]

        f32x4 acc[4][2];
#pragma unroll
        for (int i = 0; i < 4; ++i)
#pragma unroll
            for (int j = 0; j < 2; ++j) acc[i][j] = (f32x4)0.f;

        for (int chk = 0; chk < 4; ++chk) {
            short8 ah[4], al[4];
#pragma unroll
            for (int i = 0; i < 4; ++i) {
                size_t g = xb + (size_t)(nbase + i * 16 + col) * CHN + chk * 32 + koff;
                ah[i] = *(const short8*)&xhi[g];
                al[i] = *(const short8*)&xlo[g];
            }
#pragma unroll
            for (int j = 0; j < 2; ++j) {
                size_t g = (size_t)(obase + j * 16 + col) * CHN + chk * 32 + koff;
                short8 bh = *(const short8*)&whi[g];
                short8 bl = *(const short8*)&wlo[g];
#pragma unroll
                for (int i = 0; i < 4; ++i) {
                    acc[i][j] = __builtin_amdgcn_mfma_f32_16x16x32_bf16(ah[i], bh, acc[i][j], 0, 0, 0);
                    acc[i][j] = __builtin_amdgcn_mfma_f32_16x16x32_bf16(ah[i], bl, acc[i][j], 0, 0, 0);
                    acc[i][j] = __builtin_amdgcn_mfma_f32_16x16x32_bf16(al[i], bh, acc[i][j], 0, 0, 0);
                }
            }
        }
#pragma unroll
        for (int i = 0; i < 4; ++i)
#pragma unroll
            for (int j = 0; j < 2; ++j) {
                int oc = (obase + j * 16 + col) & 255;
#pragma unroll
                for (int r = 0; r < 4; ++r) {
                    int n = nbase + i * 16 + quad * 4 + r;
                    size_t off = (size_t)(b * NPTS + n) * NOUT + oc;
                    if (ot < 8) p[off] = acc[i][j][r];
                    else        q[off] = f2bf(acc[i][j][r]);
                }
            }
        return;
    }

    // ---------------- knn path ----------------
    const int q0 = blockIdx.y * 64, ms = blockIdx.z;
    const int msbase = ms * 512;
    const int mcol0 = wv * 32;
    float* dtw = &dts[wv * 64 * 36];     // this wave's private 64q x 36-stride region

    float dl[KNN]; int il[KNN];
#pragma unroll
    for (int k = 0; k < KNN; ++k) { dl[k] = FLT_MAX; il[k] = 0; }

    auto ins = [&](float v, int idx) {
        if (v < dl[KNN - 1]) {
            bool c0b = v < dl[0];
#pragma unroll
            for (int k = KNN - 1; k >= 1; --k) {
                bool sh   = v < dl[k - 1];
                bool here = v < dl[k];
                float nd = sh ? dl[k - 1] : (here ? v : dl[k]);
                int   ni = sh ? il[k - 1] : (here ? idx : il[k]);
                dl[k] = nd; il[k] = ni;
            }
            if (c0b) { dl[0] = v; il[0] = idx; }
        }
    };

    for (int iter = 0; iter < 4; ++iter) {
        const int mbase = msbase + iter * 128;
        float sm[2];
#pragma unroll
        for (int j = 0; j < 2; ++j)
            sm[j] = sqh[b * NPTS + mbase + mcol0 + j * 16 + col];

        f32x4 acc[4][2];
#pragma unroll
        for (int i = 0; i < 4; ++i)
#pragma unroll
            for (int j = 0; j < 2; ++j) acc[i][j] = (f32x4)0.f;

        for (int chk = 0; chk < 4; ++chk) {
            short8 ah[4], al[4];
#pragma unroll
            for (int i = 0; i < 4; ++i) {
                size_t g = xb + (size_t)(q0 + i * 16 + col) * CHN + chk * 32 + koff;
                ah[i] = *(const short8*)&xhi[g];
                al[i] = *(const short8*)&xlo[g];
            }
#pragma unroll
            for (int j = 0; j < 2; ++j) {
                size_t g = xb + (size_t)(mbase + mcol0 + j * 16 + col) * CHN + chk * 32 + koff;
                short8 bh = *(const short8*)&xhi[g];
                short8 bl = *(const short8*)&xlo[g];
#pragma unroll
                for (int i = 0; i < 4; ++i) {
                    acc[i][j] = __builtin_amdgcn_mfma_f32_16x16x32_bf16(ah[i], bh, acc[i][j], 0, 0, 0);
                    acc[i][j] = __builtin_amdgcn_mfma_f32_16x16x32_bf16(ah[i], bl, acc[i][j], 0, 0, 0);
                    acc[i][j] = __builtin_amdgcn_mfma_f32_16x16x32_bf16(al[i], bh, acc[i][j], 0, 0, 0);
                }
            }
        }

        // dump 64q x 32m into wave-private region — no barrier (same-wave DS ordering)
        // bank: addr/4 mod 32 = (4*q_ + c) mod 32 -> quad pairs alias 2-way = free (m136)
#pragma unroll
        for (int j = 0; j < 2; ++j)
#pragma unroll
            for (int i = 0; i < 4; ++i)
#pragma unroll
                for (int r = 0; r < 4; ++r) {
                    int q_ = i * 16 + quad * 4 + r;
                    dtw[q_ * 36 + j * 16 + col] = sm[j] - acc[i][j][r];
                }
        // scan: lane l = query q0+l, reads its own row (8x float4, stride 36 = uniform banks)
        const int ibase = mbase + mcol0;
#pragma unroll
        for (int jj = 0; jj < 8; ++jj) {
            float4 v = *(const float4*)&dtw[lane * 36 + jj * 4];
            float mn4 = fminf(fminf(v.x, v.y), fminf(v.z, v.w));
            if (mn4 < dl[KNN - 1]) {
                int ib = ibase + jj * 4;
                ins(v.x, ib); ins(v.y, ib + 1); ins(v.z, ib + 2); ins(v.w, ib + 3);
            }
        }
    }

    // merge: wave w holds query l's top-9 over its 128 cols in lane l
    __syncthreads();                     // all waves done scanning before merge-area writes
    float* md = dts;                     // 64 x 36 floats
    int*   mi = (int*)(dts + 2304);      // 64 x 36 ints
#pragma unroll
    for (int k = 0; k < KNN; ++k) {
        md[lane * 36 + wv * 9 + k] = dl[k];
        mi[lane * 36 + wv * 9 + k] = il[k];
    }
    __syncthreads();
    if (tid < 64) {
        int base = tid * 36;
        int p0 = 0, p1 = 0, p2 = 0, p3 = 0;
        size_t ob = ((size_t)(b * NPTS + q0 + tid) * 4 + ms) * KNN;
        for (int k = 0; k < KNN; ++k) {
            float v0 = (p0 < KNN) ? md[base + p0]      : FLT_MAX;
            float v1 = (p1 < KNN) ? md[base + 9 + p1]  : FLT_MAX;
            float v2 = (p2 < KNN) ? md[base + 18 + p2] : FLT_MAX;
            float v3 = (p3 < KNN) ? md[base + 27 + p3] : FLT_MAX;
            float best = v0; int sel = 0;
            if (v1 < best) { best = v1; sel = 1; }
            if (v2 < best) { best = v2; sel = 2; }
            if (v3 < best) { best = v3; sel = 3; }
            int idx;
            if      (sel == 0) { idx = mi[base + p0];      p0++; }
            else if (sel == 1) { idx = mi[base + 9 + p1];  p1++; }
            else if (sel == 2) { idx = mi[base + 18 + p2]; p2++; }
            else               { idx = mi[base + 27 + p3]; p3++; }
            pd[ob + k] = best;
            pi[ob + k] = idx;
        }
    }
}

// ---------------- kernel 3: merge FUSED + BN stats (per-batch) + packed bf16 (hmax,hmin) (R13) ------------
__global__ __launch_bounds__(256) void stats2_kernel(const float* __restrict__ p,
                                                     const unsigned short* __restrict__ q,
                                                     const float* __restrict__ pd,
                                                     const int* __restrict__ pi,
                                                     float* __restrict__ stats,
                                                     unsigned int* __restrict__ hmm) {
    __shared__ int idx_s[16 * KNN];
    const int b = blockIdx.x, n0 = blockIdx.y * 16;
    const int o = threadIdx.x;
    if (threadIdx.x < 16) {
        size_t g = (size_t)(b * NPTS + n0 + threadIdx.x) * 36;
        const float* d = pd + g;
        const int*   i = pi + g;
        int p0 = 0, p1 = 0, p2 = 0, p3 = 0;
#pragma unroll
        for (int k = 0; k < KNN; ++k) {
            float v0 = (p0 < KNN) ? d[p0]      : FLT_MAX;
            float v1 = (p1 < KNN) ? d[9 + p1]  : FLT_MAX;
            float v2 = (p2 < KNN) ? d[18 + p2] : FLT_MAX;
            float v3 = (p3 < KNN) ? d[27 + p3] : FLT_MAX;
            float best = v0; int sel = 0;
            if (v1 < best) { best = v1; sel = 1; }
            if (v2 < best) { best = v2; sel = 2; }
            if (v3 < best) { best = v3; sel = 3; }
            int idx;
            if      (sel == 0) { idx = i[p0];      p0++; }
            else if (sel == 1) { idx = i[9 + p1];  p1++; }
            else if (sel == 2) { idx = i[18 + p2]; p2++; }
            else               { idx = i[27 + p3]; p3++; }
            idx_s[threadIdx.x * KNN + k] = idx;
        }
    }
    __syncthreads();
    const unsigned short* qb = q + (size_t)b * NPTS * NOUT + o;
    float s = 0.f, ss = 0.f;
    for (int qq = 0; qq < 16; qq += 2) {
        size_t off0 = (size_t)(b * NPTS + n0 + qq) * NOUT + o;
        size_t off1 = off0 + NOUT;
        float pv0 = p[off0], pv1 = p[off1];
        float h0[KNN], h1[KNN];
#pragma unroll
        for (int k = 0; k < KNN; ++k)
            h0[k] = bf2f(qb[(size_t)idx_s[qq * KNN + k] * NOUT]);
#pragma unroll
        for (int k = 0; k < KNN; ++k)
            h1[k] = bf2f(qb[(size_t)idx_s[(qq + 1) * KNN + k] * NOUT]);
        float mx0 = -FLT_MAX, mn0 = FLT_MAX, mx1 = -FLT_MAX, mn1 = FLT_MAX;
#pragma unroll
        for (int k = 0; k < KNN; ++k) {
            float a = pv0 + h0[k], c = pv1 + h1[k];
            s += a + c; ss += a * a + c * c;
            mx0 = fmaxf(mx0, a); mn0 = fminf(mn0, a);
            mx1 = fmaxf(mx1, c); mn1 = fminf(mn1, c);
        }
        hmm[off0] = ((unsigned int)f2bf(mx0) << 16) | f2bf(mn0);
        hmm[off1] = ((unsigned int)f2bf(mx1) << 16) | f2bf(mn1);
    }
    atomicAdd(&stats[b * 512 + o], s);
    atomicAdd(&stats[b * 512 + NOUT + o], ss);
}

// ---------------- kernel 4: normalize + relu + max_k, transposed store (R13) ----------------
__global__ __launch_bounds__(256) void final_kernel(const unsigned int* __restrict__ hmm,
                                                    const float* __restrict__ stats,
                                                    const float* __restrict__ gamma,
                                                    const float* __restrict__ beta,
                                                    float* __restrict__ out) {
    __shared__ float tr[256 * 17];
    const int b = blockIdx.x, n0 = blockIdx.y * 16;
    const int o = threadIdx.x;
    float sum = 0.f, sumsq = 0.f;
#pragma unroll
    for (int i = 0; i < 8; ++i) {
        sum   += stats[i * 512 + o];
        sumsq += stats[i * 512 + NOUT + o];
    }
    const float inv = 1.f / (float)TOTCNT;
    float mean = sum * inv;
    float var  = sumsq * inv - mean * mean;
    float g    = gamma[o] / sqrtf(var + 1e-5f);
    float bet  = beta[o];
    const bool pos = (g >= 0.f);
    for (int qq = 0; qq < 16; ++qq) {
        size_t off = (size_t)(b * NPTS + n0 + qq) * NOUT + o;
        unsigned int w = hmm[off];
        float v = bf2f(pos ? (unsigned short)(w >> 16) : (unsigned short)(w & 0xFFFFu));
        float hn = (v - mean) * g + bet;
        tr[o * 17 + qq] = fmaxf(hn, 0.f);
    }
    __syncthreads();
    int oo = threadIdx.x >> 4, qq = threadIdx.x & 15;
    for (int pass = 0; pass < 16; ++pass) {
        int o_ = pass * 16 + oo;
        out[((size_t)b * NOUT + o_) * NPTS + n0 + qq] = tr[o_ * 17 + qq];
    }
}

extern "C" void kernel_launch(void* const* d_in, const int* in_sizes, int n_in,
                              void* d_out, int out_size, void* d_ws, size_t ws_size,
                              hipStream_t stream) {
    (void)in_sizes; (void)n_in; (void)out_size; (void)ws_size;
    const float* x     = (const float*)d_in[0];
    const float* W     = (const float*)d_in[1];
    const float* gamma = (const float*)d_in[2];
    const float* beta  = (const float*)d_in[3];
    float* out = (float*)d_out;

    char* ws = (char*)d_ws;
    float*          p     = (float*)ws;                                   // 16 MB fp32
    unsigned short* q     = (unsigned short*)(ws + (16u << 20));          // 8 MB bf16
    unsigned short* xhi   = (unsigned short*)(ws + (24u << 20));          // 4 MB
    unsigned short* xlo   = (unsigned short*)(ws + (28u << 20));          // 4 MB
    unsigned int*   hmm   = (unsigned int*)(ws + (32u << 20));            // 16 MB
    unsigned short* whi   = (unsigned short*)(ws + (48u << 20));          // 128 KB
    unsigned short* wlo   = (unsigned short*)(ws + (48u << 20) + 131072); // 128 KB
    float*          pd    = (float*)(ws + (49u << 20));                   // 2.25 MB
    int*            pi    = (int*)  (ws + (52u << 20));                   // 2.25 MB
    float*          sqh   = (float*)(ws + (55u << 20));                   // 64 KB
    float*          stats = (float*)(ws + (55u << 20) + 65536);           // 16 KB

    prep_kernel  <<<dim3(8, 33),    256, 0, stream>>>(x, W, xhi, xlo, whi, wlo, sqh, stats);
    knnpq_mfma   <<<dim3(8, 32, 8), 256, 0, stream>>>(xhi, xlo, sqh, whi, wlo, pd, pi, p, q);
    stats2_kernel<<<dim3(8, 128),   256, 0, stream>>>(p, q, pd, pi, stats, hmm);
    final_kernel <<<dim3(8, 128),   256, 0, stream>>>(hmm, stats, gamma, beta, out);
}